// Round 17
// baseline (191.656 us; speedup 1.0000x reference)
//
#include <hip/hip_runtime.h>

// Problem constants (B=1)
#define R_   384
#define P_   (R_ * R_)      // 147456 pairs
#define NT_  4              // templates
#define CIN  128            // z channels
#define CKV  64             // t channels
#define NH   4              // heads
#define HC   256            // NH * 64

// Tiling
#define TP   64             // pairs per block (256 threads, 4 waves)
#define LDT  264            // T/U row stride (bf16) in sT: 528B rows

typedef __attribute__((ext_vector_type(8))) short bf16x8;
typedef __attribute__((ext_vector_type(4))) float f32x4;
typedef __attribute__((ext_vector_type(4))) uint  u32x4;

// round-to-nearest-even f32 -> bf16 (bit-level, no HIP class types)
__device__ __forceinline__ ushort f2bf_s(float f) {
    uint32_t u = __float_as_uint(f);
    u += 0x7FFFu + ((u >> 16) & 1u);
    return (ushort)(u >> 16);
}
__device__ __forceinline__ uint packbf2(float lo, float hi) {
    return (uint)f2bf_s(lo) | ((uint)f2bf_s(hi) << 16);
}
__device__ __forceinline__ uint2 pack4(const float4 v) {
    uint2 r; r.x = packbf2(v.x, v.y); r.y = packbf2(v.z, v.w); return r;
}
__device__ __forceinline__ float bflo(uint t) { return __uint_as_float(t << 16); }
__device__ __forceinline__ float bfhi(uint t) { return __uint_as_float(t & 0xffff0000u); }

union BF8 { bf16x8 v; uint u[4]; };

// ---------------------------------------------------------------------------
// Precompute Mt (ROW-PERMUTED, verified r15/r16) and Gt.
//   Mt logical row n = h*64 + j stored at row h*64 + perm(j),
//   perm(j) = ((j>>2)&3)*16 + (j>>4)*4 + (j&3): swapped-GEMM1's lane g then
//   holds contiguous original channels [g*16, g*16+16) of each head.
// ---------------------------------------------------------------------------
__global__ __launch_bounds__(256) void precompute_mg(
        const float* __restrict__ Wq, const float* __restrict__ Wk,
        const float* __restrict__ Wv, const float* __restrict__ Wo,
        ushort* __restrict__ Mt, ushort* __restrict__ Gt) {
    int tid = blockIdx.x * blockDim.x + threadIdx.x;
    if (tid < HC * CIN) {
        int n = tid >> 7, ci = tid & 127;
        int h = n >> 6, j = n & 63;
        float acc = 0.f;
        for (int c = 0; c < 64; ++c)
            acc += Wq[ci * HC + h * 64 + c] * Wk[j * HC + h * 64 + c];
        int jp = ((j >> 2) & 3) * 16 + (j >> 4) * 4 + (j & 3);   // permute
        Mt[(h * 64 + jp) * CIN + ci] = f2bf_s(acc * 0.125f);     // C^-0.5 = 1/8
    } else {
        int t = tid - HC * CIN;
        int co = t >> 8, n = t & 255;
        int h = n >> 6, j = n & 63;
        float acc = 0.f;
        for (int c = 0; c < 64; ++c)
            acc += Wv[j * HC + h * 64 + c] * Wo[(h * 64 + c) * CIN + co];
        Gt[co * HC + n] = f2bf_s(acc);
    }
}

// ---------------------------------------------------------------------------
// Fused kernel, LDS = sT only (33.8 KB) -> 4 blocks/CU.
//   stage T -> sT (ds_writes drain under GEMM1) ;
//   GEMM1 swapped, Z fragments DIRECT FROM GLOBAL (L2/L1-resident tile),
//     A stays in fp32 regs (permuted Mt, r15/r16-verified) ;
//   bar1 ; B2/bias issue ; middle (T from sT, logits+softmax+U -> regs) ;
//   bar2 ; U overwrites sT in place ; bar3 ;
//   GEMM2 swapped (float4 stores, r7-verified) ; bias ; store.  3 barriers.
// ---------------------------------------------------------------------------
__global__ __launch_bounds__(256, 4) void tpa_fused(
        const float* __restrict__ z2d, const float* __restrict__ t2d,
        const ushort* __restrict__ Mt, const ushort* __restrict__ Gt,
        const float* __restrict__ bo, float* __restrict__ out) {

    __shared__ ushort sT[TP * LDT];   // T bf16, then U bf16 (in place): 33792 B

    const int tid  = threadIdx.x;
    const int lane = tid & 63;
    const int wv   = tid >> 6;           // wave == head
    const int lr   = lane & 15;
    const int g    = lane >> 4;          // 0..3
    const int g8   = g << 3;
    const int pg0  = blockIdx.x * TP;

    // ---- B1 fragments (L2-resident, permuted Mt) --------------------------
    bf16x8 B1[4][4];   // [kt][nt]
    #pragma unroll
    for (int kt = 0; kt < 4; ++kt)
        #pragma unroll
        for (int nt = 0; nt < 4; ++nt)
            B1[kt][nt] = *(const bf16x8*)(Mt + (wv * 64 + nt * 16 + lr) * CIN + kt * 32 + g8);

    // ---- stage T: 4 x (64 x 64) fp32 -> bf16 (ds_writes drain under GEMM1)
    #pragma unroll
    for (int k = 0; k < NT_; ++k) {
        const float* src = t2d + ((size_t)k * P_ + pg0) * CKV;
        #pragma unroll
        for (int i = 0; i < 4; ++i) {
            int idx = (i * 256 + tid) * 4, p = idx >> 6, c = idx & 63;
            float4 v = *(const float4*)(src + p * 64 + c);
            *(uint2*)&sT[p * LDT + k * 64 + c] = pack4(v);
        }
    }

    // ---- GEMM1 (swapped): Z fragments direct from global ------------------
    //      lane (g,lr) holds, for p = mt*16+lr:
    //      acc1[nt][mt][r] = A[p][wv*64 + g*16 + nt*4 + r]  (fp32, permuted Mt)
    f32x4 acc1[4][4];
    #pragma unroll
    for (int nt = 0; nt < 4; ++nt)
        #pragma unroll
        for (int mt = 0; mt < 4; ++mt)
            acc1[nt][mt] = (f32x4){0.f, 0.f, 0.f, 0.f};
    #pragma unroll
    for (int kt = 0; kt < 4; ++kt) {
        bf16x8 zf[4];
        #pragma unroll
        for (int mt = 0; mt < 4; ++mt) {
            const float* zp = z2d + (size_t)(pg0 + mt * 16 + lr) * CIN + kt * 32 + g8;
            float4 z0 = *(const float4*)zp;
            float4 z1 = *(const float4*)(zp + 4);
            BF8 zb;
            zb.u[0] = packbf2(z0.x, z0.y); zb.u[1] = packbf2(z0.z, z0.w);
            zb.u[2] = packbf2(z1.x, z1.y); zb.u[3] = packbf2(z1.z, z1.w);
            zf[mt] = zb.v;
        }
        #pragma unroll
        for (int nt = 0; nt < 4; ++nt)
            #pragma unroll
            for (int mt = 0; mt < 4; ++mt)
                acc1[nt][mt] = __builtin_amdgcn_mfma_f32_16x16x32_bf16(
                    B1[kt][nt], zf[mt], acc1[nt][mt], 0, 0, 0);
    }
    __syncthreads();   // bar1: T staged (drained under GEMM1), visible to all

    // ---- B2 + bias (L2 latency hides under middle) -------------------------
    bf16x8 B2[8][2];   // [kt][nt], wave wv -> out cols [wv*32, +32)
    #pragma unroll
    for (int kt = 0; kt < 8; ++kt)
        #pragma unroll
        for (int nt = 0; nt < 2; ++nt)
            B2[kt][nt] = *(const bf16x8*)(Gt + (wv * 32 + nt * 16 + lr) * HC + kt * 32 + g8);
    float4 b4[2];
    #pragma unroll
    for (int nt = 0; nt < 2; ++nt)
        b4[nt] = *(const float4*)(bo + wv * 32 + nt * 16 + g * 4);

    // ---- middle: per mt, pair p = mt*16+lr; lane owns head wv,
    //      channels [g*16, +16). U accumulates into regs.
    u32x4 ureg[4][2];
    #pragma unroll
    for (int mt = 0; mt < 4; ++mt) {
        const int p = mt * 16 + lr;
        u32x4 tq[NT_][2];                 // T[p][k*64 + g*16 .. +16), bf16
        #pragma unroll
        for (int k = 0; k < NT_; ++k) {
            tq[k][0] = *(const u32x4*)&sT[p * LDT + k * 64 + g * 16];
            tq[k][1] = *(const u32x4*)&sT[p * LDT + k * 64 + g * 16 + 8];
        }
        float lg[4];
        #pragma unroll
        for (int k = 0; k < NT_; ++k) {
            float s = 0.f;
            #pragma unroll
            for (int nt = 0; nt < 4; ++nt)
                #pragma unroll
                for (int r = 0; r < 4; ++r) {
                    int cc = nt * 4 + r;
                    uint tw = tq[k][cc >> 3][(cc >> 1) & 3];
                    float tv = (cc & 1) ? bfhi(tw) : bflo(tw);
                    s = fmaf(acc1[nt][mt][r], tv, s);
                }
            s += __shfl_xor(s, 16);       // combine 4 g-quarters
            s += __shfl_xor(s, 32);
            lg[k] = s;
        }
        float mx = fmaxf(fmaxf(lg[0], lg[1]), fmaxf(lg[2], lg[3]));
        float w0 = __expf(lg[0] - mx), w1 = __expf(lg[1] - mx);
        float w2 = __expf(lg[2] - mx), w3 = __expf(lg[3] - mx);
        float inv = 1.f / (w0 + w1 + w2 + w3);
        w0 *= inv; w1 *= inv; w2 *= inv; w3 *= inv;

        #pragma unroll
        for (int j = 0; j < 2; ++j) {
            u32x4 o;
            #pragma unroll
            for (int e = 0; e < 4; ++e) {
                uint t0 = tq[0][j][e], t1 = tq[1][j][e];
                uint t2 = tq[2][j][e], t3 = tq[3][j][e];
                float lo = w0 * bflo(t0) + w1 * bflo(t1) + w2 * bflo(t2) + w3 * bflo(t3);
                float hi = w0 * bfhi(t0) + w1 * bfhi(t1) + w2 * bfhi(t2) + w3 * bfhi(t3);
                o[e] = packbf2(lo, hi);
            }
            ureg[mt][j] = o;
        }
    }
    __syncthreads();   // bar2: ALL T reads done before any U overwrite

    // ---- U overwrites sT in place: row p, cols [wv*64 + g*16, +16) ---------
    #pragma unroll
    for (int mt = 0; mt < 4; ++mt) {
        const int p = mt * 16 + lr;
        *(u32x4*)&sT[p * LDT + wv * 64 + g * 16]     = ureg[mt][0];
        *(u32x4*)&sT[p * LDT + wv * 64 + g * 16 + 8] = ureg[mt][1];
    }
    __syncthreads();   // bar3: U visible to all waves

    // ---- GEMM2 (swapped, r7-verified): acc2[nt][mt] = OUT^T tile -----------
    //      D[row = co-in-16 (g*4+r)][col = p-in-16 (lr)]
    f32x4 acc2[2][4];
    #pragma unroll
    for (int nt = 0; nt < 2; ++nt)
        #pragma unroll
        for (int mt = 0; mt < 4; ++mt)
            acc2[nt][mt] = (f32x4){0.f, 0.f, 0.f, 0.f};
    #pragma unroll
    for (int kt = 0; kt < 8; ++kt) {
        bf16x8 uf[4];
        #pragma unroll
        for (int mt = 0; mt < 4; ++mt)
            uf[mt] = *(const bf16x8*)&sT[(mt * 16 + lr) * LDT + kt * 32 + g8];
        #pragma unroll
        for (int nt = 0; nt < 2; ++nt)
            #pragma unroll
            for (int mt = 0; mt < 4; ++mt)
                acc2[nt][mt] = __builtin_amdgcn_mfma_f32_16x16x32_bf16(
                    B2[kt][nt], uf[mt], acc2[nt][mt], 0, 0, 0);
    }

    // ---- epilogue: bias + contiguous float4 stores --------------------------
    #pragma unroll
    for (int nt = 0; nt < 2; ++nt) {
        int co0 = wv * 32 + nt * 16 + g * 4;
        #pragma unroll
        for (int mt = 0; mt < 4; ++mt) {
            int p = mt * 16 + lr;
            float4 o;
            o.x = acc2[nt][mt][0] + b4[nt].x;
            o.y = acc2[nt][mt][1] + b4[nt].y;
            o.z = acc2[nt][mt][2] + b4[nt].z;
            o.w = acc2[nt][mt][3] + b4[nt].w;
            *(float4*)(out + (size_t)(pg0 + p) * CIN + co0) = o;
        }
    }
}

extern "C" void kernel_launch(void* const* d_in, const int* in_sizes, int n_in,
                              void* d_out, int out_size, void* d_ws, size_t ws_size,
                              hipStream_t stream) {
    const float* z2d = (const float*)d_in[0];
    const float* t2d = (const float*)d_in[1];
    const float* Wq  = (const float*)d_in[2];
    const float* Wk  = (const float*)d_in[3];
    const float* Wv  = (const float*)d_in[4];
    const float* Wo  = (const float*)d_in[5];
    const float* bo  = (const float*)d_in[6];

    ushort* Mt = (ushort*)d_ws;            // 256x128 bf16 (row-permuted)
    ushort* Gt = Mt + HC * CIN;            // 128x256 bf16

    precompute_mg<<<(2 * HC * CIN) / 256, 256, 0, stream>>>(Wq, Wk, Wv, Wo, Mt, Gt);
    tpa_fused<<<P_ / TP, 256, 0, stream>>>(z2d, t2d, Mt, Gt, bo, (float*)d_out);
}